// Round 8
// baseline (6531.489 us; speedup 1.0000x reference)
//
#include <hip/hip_runtime.h>
#include <hip/hip_bf16.h>
#include <stdint.h>

#define SEQ   512
#define BATCH 256
#define EMBD  256
#define HID   512
#define OUTD  4

typedef float  f32x4 __attribute__((ext_vector_type(4)));
typedef short  s16x8 __attribute__((ext_vector_type(8)));
typedef __bf16 bf16x8 __attribute__((ext_vector_type(8)));

static __device__ __forceinline__ short f2bf(float f) {
    union { float f; uint32_t u; } v; v.f = f;
    uint32_t u = v.u;
    u += 0x7fffu + ((u >> 16) & 1u);      // round-to-nearest-even
    return (short)(u >> 16);
}
static __device__ __forceinline__ float bf2f(short s) {
    union { uint32_t u; float f; } v;
    v.u = ((uint32_t)(uint16_t)s) << 16;
    return v.f;
}

static __device__ __forceinline__ f32x4 mfma_bf16(s16x8 a, s16x8 b, f32x4 c) {
    return __builtin_amdgcn_mfma_f32_16x16x32_bf16(
        __builtin_bit_cast(bf16x8, a), __builtin_bit_cast(bf16x8, b), c, 0, 0, 0);
}

// Agent-coherent (L1/L2-bypassing) accesses — validated in round 2.
static __device__ __forceinline__ s16x8 load_coherent_b128(const void* p) {
    s16x8 r;
    asm volatile("global_load_dwordx4 %0, %1, off sc0 sc1"
                 : "=v"(r) : "v"(p) : "memory");
    return r;
}
static __device__ __forceinline__ void store_coherent_b128(void* p, s16x8 v) {
    asm volatile("global_store_dwordx4 %0, %1, off sc0 sc1"
                 :: "v"(p), "v"(v) : "memory");
}
static __device__ __forceinline__ void wait_vm0() {
    asm volatile("s_waitcnt vmcnt(0)" ::: "memory");
    __builtin_amdgcn_sched_barrier(0);   // rule #18
}
static __device__ __forceinline__ void spin_ms(int ms) {
    // s_sleep 8 ~ 512 clk @2.4GHz ~ 0.213us; 4700 iters ~ 1ms
    for (int i = 0; i < ms * 4700; ++i)
        asm volatile("s_sleep 8" ::: "memory");
}

// ---------------------------------------------------------------------------
// Kernel 1: xp(bf16) = emb[text] @ W_ih^T + b_ih + b_hh   (r2-validated)
// ---------------------------------------------------------------------------
__global__ __launch_bounds__(512, 1)
void xproj_kernel(const int* __restrict__ text, const float* __restrict__ emb,
                  const float* __restrict__ W_ih, const float* __restrict__ b_ih,
                  const float* __restrict__ b_hh, short* __restrict__ xp) {
    extern __shared__ char lds[];
    char* As = lds;
    char* Bs = lds + 65536;

    const int t    = threadIdx.x;
    const int row0 = blockIdx.x * 128;
    const int col0 = blockIdx.y * 128;

    {
        const int r   = t >> 2;
        const int kc  = (t & 3) * 64;
        const int tok = text[row0 + r];
        const float* src = emb + (size_t)tok * EMBD + kc;
        #pragma unroll
        for (int u = 0; u < 64; u += 8) {
            f32x4 x0 = *(const f32x4*)(src + u);
            f32x4 x1 = *(const f32x4*)(src + u + 4);
            s16x8 pk;
            pk[0]=f2bf(x0.x); pk[1]=f2bf(x0.y); pk[2]=f2bf(x0.z); pk[3]=f2bf(x0.w);
            pk[4]=f2bf(x1.x); pk[5]=f2bf(x1.y); pk[6]=f2bf(x1.z); pk[7]=f2bf(x1.w);
            int byte = (r * 512 + (kc + u) * 2) ^ ((r & 7) << 4);
            *(s16x8*)(As + byte) = pk;
        }
    }
    {
        const int c  = t >> 2;
        const int kc = (t & 3) * 64;
        const float* src = W_ih + (size_t)(col0 + c) * EMBD + kc;
        #pragma unroll
        for (int u = 0; u < 64; u += 8) {
            f32x4 x0 = *(const f32x4*)(src + u);
            f32x4 x1 = *(const f32x4*)(src + u + 4);
            s16x8 pk;
            pk[0]=f2bf(x0.x); pk[1]=f2bf(x0.y); pk[2]=f2bf(x0.z); pk[3]=f2bf(x0.w);
            pk[4]=f2bf(x1.x); pk[5]=f2bf(x1.y); pk[6]=f2bf(x1.z); pk[7]=f2bf(x1.w);
            int byte = (c * 512 + (kc + u) * 2) ^ ((c & 7) << 4);
            *(s16x8*)(Bs + byte) = pk;
        }
    }
    __syncthreads();

    const int lane = t & 63;
    const int w    = t >> 6;
    const int wm   = w >> 2;
    const int wn   = w & 3;
    const int lr   = lane & 15;
    const int lk   = (lane >> 4) * 8;

    f32x4 acc[4][2] = {};
    #pragma unroll
    for (int kk = 0; kk < 8; ++kk) {
        s16x8 a[4], b[2];
        #pragma unroll
        for (int mt = 0; mt < 4; ++mt) {
            int r = wm * 64 + mt * 16 + lr;
            int byte = (r * 512 + (kk * 32 + lk) * 2) ^ ((r & 7) << 4);
            a[mt] = *(const s16x8*)(As + byte);
        }
        #pragma unroll
        for (int nt = 0; nt < 2; ++nt) {
            int c = wn * 32 + nt * 16 + lr;
            int byte = (c * 512 + (kk * 32 + lk) * 2) ^ ((c & 7) << 4);
            b[nt] = *(const s16x8*)(Bs + byte);
        }
        #pragma unroll
        for (int mt = 0; mt < 4; ++mt)
            #pragma unroll
            for (int nt = 0; nt < 2; ++nt)
                acc[mt][nt] = mfma_bf16(a[mt], b[nt], acc[mt][nt]);
    }

    #pragma unroll
    for (int nt = 0; nt < 2; ++nt) {
        const int c = col0 + wn * 32 + nt * 16 + lr;
        const float bias = b_ih[c] + b_hh[c];
        #pragma unroll
        for (int mt = 0; mt < 4; ++mt) {
            #pragma unroll
            for (int r4 = 0; r4 < 4; ++r4) {
                const int rr = row0 + wm * 64 + mt * 16 + (lane >> 4) * 4 + r4;
                xp[(size_t)rr * HID + c] = f2bf(acc[mt][nt][r4] + bias);
            }
        }
    }
}

// ---------------------------------------------------------------------------
// Wp pack: cols 384..511 of W_hh as bf16 B-fragments in load order:
// block flat = (g*16+kk)*64 + lane  (lane = hi*16+lr), 8 bf16 each ->
// col 384+g*16+lr, k = kk*32+hi*8..+7. Probe D2 reads 1KB fully coalesced.
// ---------------------------------------------------------------------------
__global__ void wprep_pack(const float* __restrict__ W, short* __restrict__ Wp) {
    const int id = blockIdx.x * 256 + threadIdx.x;   // 0..8191
    if (id >= 8192) return;
    const int lane = id & 63;
    const int lr = lane & 15, hi = lane >> 4;
    const int gk = id >> 6;                 // 0..127
    const int kk = gk & 15, g = gk >> 4;    // kk 0..15, g 0..7
    const int col = 384 + g * 16 + lr;
    const int k0  = kk * 32 + hi * 8;
    const float* src = W + (size_t)col * HID + k0;
    f32x4 x0 = *(const f32x4*)(src);
    f32x4 x1 = *(const f32x4*)(src + 4);
    s16x8 pk;
    pk[0]=f2bf(x0.x); pk[1]=f2bf(x0.y); pk[2]=f2bf(x0.z); pk[3]=f2bf(x0.w);
    pk[4]=f2bf(x1.x); pk[5]=f2bf(x1.y); pk[6]=f2bf(x1.z); pk[7]=f2bf(x1.w);
    *(s16x8*)(Wp + (size_t)id * 8) = pk;
}

// ---------------------------------------------------------------------------
// Kernel 2: r2-validated recurrence (writes d_out). Unchanged.
// ---------------------------------------------------------------------------
__global__ __launch_bounds__(256, 1)
void rnn_kernel(const float* __restrict__ W_hh, const short* __restrict__ xp,
                const float* __restrict__ fc_w, const float* __restrict__ fc_b,
                short* __restrict__ hbuf, unsigned int* __restrict__ bar,
                float* __restrict__ out) {
    extern __shared__ char lds[];
    short* hstage = (short*)(lds + 131072);

    const int bid  = blockIdx.x;
    const int gi   = (bid & 7) + ((bid >> 5) << 3);
    const int gj   = (bid >> 3) & 3;
    const int t    = threadIdx.x;
    const int lane = t & 63;
    const int w    = t >> 6;
    const int row0 = gi * 16;
    const int col0 = gj * 128;

    {
        const int c  = t >> 1;
        const int k0 = (t & 1) * 256;
        const float* src = W_hh + (size_t)(col0 + c) * HID + k0;
        #pragma unroll 4
        for (int u = 0; u < 256; u += 8) {
            f32x4 x0 = *(const f32x4*)(src + u);
            f32x4 x1 = *(const f32x4*)(src + u + 4);
            s16x8 pk;
            pk[0]=f2bf(x0.x); pk[1]=f2bf(x0.y); pk[2]=f2bf(x0.z); pk[3]=f2bf(x0.w);
            pk[4]=f2bf(x1.x); pk[5]=f2bf(x1.y); pk[6]=f2bf(x1.z); pk[7]=f2bf(x1.w);
            int byte = (c * 1024 + (k0 + u) * 2) ^ ((c & 7) << 4);
            *(s16x8*)(lds + byte) = pk;
        }
    }
    __syncthreads();

    const int lr    = lane & 15;
    const int lkb   = (lane >> 4) * 16;
    const int arow  = row0 + lr;
    const int crow0 = row0 + (lane >> 4) * 4;
    unsigned int* mybar = bar + gi;

    int p = 0;
    for (int s = 0; s < SEQ; ++s) {
        f32x4 acc[2];
        #pragma unroll
        for (int nt = 0; nt < 2; ++nt) {
            const int c = col0 + w * 32 + nt * 16 + lr;
            const short* xs = xp + ((size_t)s * BATCH + crow0) * HID + c;
            #pragma unroll
            for (int r = 0; r < 4; ++r) acc[nt][r] = bf2f(xs[(size_t)r * HID]);
        }

        if (s > 0) {
            if (t == 0) {
                const unsigned int target = 4u * (unsigned int)s;
                int guard = 0;
                while (__hip_atomic_load(mybar, __ATOMIC_RELAXED,
                                         __HIP_MEMORY_SCOPE_AGENT) < target) {
                    __builtin_amdgcn_s_sleep(1);
                    if (++guard > (1 << 27)) break;
                }
            }
            __syncthreads();
        }

        const short* hb   = hbuf + (size_t)p * (BATCH * HID);
        const char*  hrow = (const char*)(hb + (size_t)arow * HID);
        s16x8 areg[16];
        #pragma unroll
        for (int kk = 0; kk < 16; ++kk)
            areg[kk] = load_coherent_b128(hrow + kk * 64 + lkb);
        wait_vm0();

        const int cl0 = w * 32 + lr;
        const int cl1 = cl0 + 16;
        #pragma unroll
        for (int kk = 0; kk < 16; ++kk) {
            const int b0b = (cl0 * 1024 + kk * 64 + lkb) ^ ((cl0 & 7) << 4);
            const int b1b = (cl1 * 1024 + kk * 64 + lkb) ^ ((cl1 & 7) << 4);
            const s16x8 b0v = *(const s16x8*)(lds + b0b);
            const s16x8 b1v = *(const s16x8*)(lds + b1b);
            acc[0] = mfma_bf16(areg[kk], b0v, acc[0]);
            acc[1] = mfma_bf16(areg[kk], b1v, acc[1]);
        }

        #pragma unroll
        for (int nt = 0; nt < 2; ++nt) {
            const int cl = w * 32 + nt * 16 + lr;
            #pragma unroll
            for (int r = 0; r < 4; ++r)
                hstage[((crow0 - row0) + r) * 128 + cl] = f2bf(tanhf(acc[nt][r]));
        }
        __syncthreads();

        {
            const int rr = t >> 4, c8 = (t & 15) * 8;
            s16x8 v = *(const s16x8*)(hstage + rr * 128 + c8);
            short* hn = hbuf + (size_t)(p ^ 1) * (BATCH * HID)
                             + (size_t)(row0 + rr) * HID + (col0 + c8);
            store_coherent_b128(hn, v);
        }
        __syncthreads();

        if (t == 0)
            __hip_atomic_fetch_add(mybar, 1u, __ATOMIC_RELAXED,
                                   __HIP_MEMORY_SCOPE_AGENT);
        p ^= 1;
    }

    if (gj == 0) {
        if (t == 0) {
            int guard = 0;
            while (__hip_atomic_load(mybar, __ATOMIC_RELAXED,
                                     __HIP_MEMORY_SCOPE_AGENT) < 4u * SEQ) {
                __builtin_amdgcn_s_sleep(1);
                if (++guard > (1 << 27)) break;
            }
        }
        __syncthreads();

        const int i  = t >> 2;
        const int q  = t & 3;
        const int bl = i >> 2;
        const int o  = i & 3;
        const short* hb = hbuf + (size_t)p * (BATCH * HID)
                               + (size_t)(row0 + bl) * HID + q * 128;
        s16x8 hv[16];
        #pragma unroll
        for (int kk = 0; kk < 16; ++kk)
            hv[kk] = load_coherent_b128((const char*)hb + kk * 16);
        wait_vm0();
        float sum = 0.f;
        #pragma unroll
        for (int kk = 0; kk < 16; ++kk)
            #pragma unroll
            for (int j = 0; j < 8; ++j)
                sum += bf2f(hv[kk][j]) * fc_w[o * HID + q * 128 + kk * 8 + j];
        sum += __shfl_xor(sum, 1);
        sum += __shfl_xor(sum, 2);
        if (q == 0)
            out[(row0 + bl) * OUTD + o] = sum + fc_b[o];
    }
}

// ---------------------------------------------------------------------------
// PROBE BODY (writes nothing to d_out). Self-contained recurrence:
// 16 WGs x 512 thr; LDS = W cols 0..127 (128KB, swz) + 2x16KB h.
// xp folded into MFMA C-init (no xpv regs).
// MODE 2: W cols 128..383 in 128 VGPRs + cols 384..511 streamed from packed
//         global Wp (coalesced 1KB/wave loads).  [~204 regs, safe]
// MODE 3: W cols 128..511 in 192 VGPRs.          [~230 regs, tight]
// Verdict vs validated h (href): clean = no spin; NaN/mis = mode-coded spin.
// ---------------------------------------------------------------------------
template <int MODE>
static __device__ __forceinline__
void probe_body(const float* W_hh, const short* Wp, const short* xp,
                const short* href, int nan_ms, int mis_ms) {
    extern __shared__ char lds[];
    char* Wl = lds;
    char* hB = lds + 131072;

    const int t    = threadIdx.x;
    const int lane = t & 63;
    const int w    = t >> 6;
    const int lr   = lane & 15;
    const int hi   = lane >> 4;
    const int row0 = blockIdx.x * 16;

    {   // W cols 0..127 -> LDS
        const int c  = t >> 2;
        const int k0 = (t & 3) * 128;
        const float* src = W_hh + (size_t)c * HID + k0;
        #pragma unroll 4
        for (int u = 0; u < 128; u += 8) {
            f32x4 x0 = *(const f32x4*)(src + u);
            f32x4 x1 = *(const f32x4*)(src + u + 4);
            s16x8 pk;
            pk[0]=f2bf(x0.x); pk[1]=f2bf(x0.y); pk[2]=f2bf(x0.z); pk[3]=f2bf(x0.w);
            pk[4]=f2bf(x1.x); pk[5]=f2bf(x1.y); pk[6]=f2bf(x1.z); pk[7]=f2bf(x1.w);
            int byte = (c * 1024 + (k0 + u) * 2) ^ ((c & 7) << 4);
            *(s16x8*)(Wl + byte) = pk;
        }
    }
    {   // zero both h buffers
        s16x8 z;
        #pragma unroll
        for (int i = 0; i < 8; ++i) z[i] = 0;
        *(s16x8*)(hB + t * 32) = z;
        *(s16x8*)(hB + 16384 + t * 32) = z;
    }
    // W reg-cols
    constexpr int NREG = (MODE == 2) ? 2 : 3;
    constexpr int WSTRIDE = (MODE == 2) ? 32 : 48;
    s16x8 wr[NREG][16];
    {
        #pragma unroll
        for (int g = 0; g < NREG; ++g) {
            const float* sg = W_hh + (size_t)(128 + w * WSTRIDE + g * 16 + lr) * HID + hi * 8;
            #pragma unroll
            for (int kk = 0; kk < 16; ++kk) {
                f32x4 a0 = *(const f32x4*)(sg + kk * 32);
                f32x4 a1 = *(const f32x4*)(sg + kk * 32 + 4);
                s16x8 pk;
                pk[0]=f2bf(a0.x); pk[1]=f2bf(a0.y); pk[2]=f2bf(a0.z); pk[3]=f2bf(a0.w);
                pk[4]=f2bf(a1.x); pk[5]=f2bf(a1.y); pk[6]=f2bf(a1.z); pk[7]=f2bf(a1.w);
                wr[g][kk] = pk;
            }
        }
    }
    __syncthreads();

    const int crow = hi * 4;
    const int swzL = (lr & 7) << 4;
    const int colL = w * 16 + lr;
    // output col per acc-slot
    int colv[4];
    colv[0] = colL;
    #pragma unroll
    for (int g = 0; g < NREG; ++g) colv[1 + g] = 128 + w * WSTRIDE + g * 16 + lr;
    if (MODE == 2) colv[3] = 384 + w * 16 + lr;

    int p = 0;
    #pragma unroll 1
    for (int s = 0; s < SEQ; ++s) {
        const char* hc = hB + p * 16384;
        char*       hn = hB + (p ^ 1) * 16384;

        // acc init = xp (bf16 -> f32), folded into MFMA C
        f32x4 acc[4];
        {
            const short* xs = xp + ((size_t)s * BATCH + row0 + crow) * HID;
            #pragma unroll
            for (int ti = 0; ti < 4; ++ti)
                #pragma unroll
                for (int r = 0; r < 4; ++r)
                    acc[ti][r] = bf2f(xs[(size_t)r * HID + colv[ti]]);
        }

        if constexpr (MODE == 2) {
            #pragma unroll
            for (int half = 0; half < 2; ++half) {
                s16x8 st[8];
                #pragma unroll
                for (int j = 0; j < 8; ++j)
                    st[j] = *(const s16x8*)(
                        Wp + ((size_t)((w * 16 + half * 8 + j) * 64 + lane)) * 8);
                #pragma unroll
                for (int j = 0; j < 8; ++j) {
                    const int kk = half * 8 + j;
                    const int kb = kk * 64 + hi * 16;
                    const s16x8 a  = *(const s16x8*)(hc + ((lr * 1024 + kb) ^ swzL));
                    const s16x8 bl = *(const s16x8*)(Wl + ((colL * 1024 + kb) ^ swzL));
                    acc[0] = mfma_bf16(a, bl,        acc[0]);
                    acc[1] = mfma_bf16(a, wr[0][kk], acc[1]);
                    acc[2] = mfma_bf16(a, wr[1][kk], acc[2]);
                    acc[3] = mfma_bf16(a, st[j],     acc[3]);
                }
            }
        } else {
            #pragma unroll
            for (int kk = 0; kk < 16; ++kk) {
                const int kb = kk * 64 + hi * 16;
                const s16x8 a  = *(const s16x8*)(hc + ((lr * 1024 + kb) ^ swzL));
                const s16x8 bl = *(const s16x8*)(Wl + ((colL * 1024 + kb) ^ swzL));
                acc[0] = mfma_bf16(a, bl,        acc[0]);
                acc[1] = mfma_bf16(a, wr[0][kk], acc[1]);
                acc[2] = mfma_bf16(a, wr[1][kk], acc[2]);
                acc[3] = mfma_bf16(a, wr[2][kk], acc[3]);
            }
        }

        // h_new = tanh(acc) -> other buffer (swizzled scalar writes)
        #pragma unroll
        for (int ti = 0; ti < 4; ++ti) {
            #pragma unroll
            for (int r = 0; r < 4; ++r) {
                const float hv = tanhf(acc[ti][r]);
                const int rr = crow + r;
                *(short*)(hn + ((rr * 1024 + colv[ti] * 2) ^ ((rr & 7) << 4))) = f2bf(hv);
            }
        }
        __syncthreads();
        p ^= 1;
    }

    // verdict: final h in buffer 0; flg region = buffer 1 (free)
    {
        int* flg = (int*)(hB + 16384);
        if (t == 0) { flg[0] = 0; flg[1] = 0; }
        __syncthreads();
        const char* hf = hB;
        const int rr = t >> 5;
        const int c0 = (t & 31) * 16;
        const int fswz = (rr & 7) << 4;
        const short* hr = href + (size_t)(row0 + rr) * HID + c0;
        s16x8 r0 = load_coherent_b128(hr);
        s16x8 r1 = load_coherent_b128(hr + 8);
        wait_vm0();
        int bad_nan = 0, bad_mis = 0;
        #pragma unroll
        for (int j = 0; j < 16; ++j) {
            const int c = c0 + j;
            const float a = bf2f(*(const short*)(hf + ((rr * 1024 + c * 2) ^ fswz)));
            const float b = bf2f((j < 8) ? r0[j] : r1[j - 8]);
            if (!(a == a)) bad_nan = 1;
            else if (!(fabsf(a - b) <= 0.02f)) bad_mis = 1;
        }
        if (bad_nan) flg[0] = 1;
        if (bad_mis) flg[1] = 1;
        __syncthreads();
        if (flg[0]) spin_ms(nan_ms);
        else if (flg[1]) spin_ms(mis_ms);
    }
}

__global__ __launch_bounds__(512, 2)
void rnn_probeD2(const float* __restrict__ W_hh, const short* __restrict__ Wp,
                 const short* __restrict__ xp, const short* __restrict__ href) {
    probe_body<2>(W_hh, Wp, xp, href, 11, 22);
}
__global__ __launch_bounds__(512, 2)
void rnn_probeD3(const float* __restrict__ W_hh, const short* __restrict__ Wp,
                 const short* __restrict__ xp, const short* __restrict__ href) {
    probe_body<3>(W_hh, Wp, xp, href, 33, 66);
}

// ---------------------------------------------------------------------------
extern "C" void kernel_launch(void* const* d_in, const int* in_sizes, int n_in,
                              void* d_out, int out_size, void* d_ws, size_t ws_size,
                              hipStream_t stream) {
    (void)in_sizes; (void)n_in; (void)out_size;
    const int*   text = (const int*)  d_in[0];
    const float* emb  = (const float*)d_in[1];
    const float* W_ih = (const float*)d_in[2];
    const float* W_hh = (const float*)d_in[3];
    const float* b_ih = (const float*)d_in[4];
    const float* b_hh = (const float*)d_in[5];
    const float* fc_w = (const float*)d_in[6];
    const float* fc_b = (const float*)d_in[7];
    float* out = (float*)d_out;

    char* ws = (char*)d_ws;
    short*        hbuf = (short*)ws;                        // 512 KB
    unsigned int* bar  = (unsigned int*)(ws + (512 << 10));
    short*        xpbf = (short*)(ws + (1 << 20));          // bf16 xp, 128 MiB

    const size_t xp_bytes = (size_t)SEQ * BATCH * HID * 2;  // 134217728
    const size_t need     = ((size_t)1 << 20) + xp_bytes;
    if (ws_size < need) return;
    const bool probe_ok = ws_size >= need + 262144;
    short* Wp = (short*)(ws + need);                        // 128 KB packed

    hipMemsetAsync(ws, 0, (512 << 10) + 4096, stream);

    hipFuncSetAttribute(reinterpret_cast<const void*>(&xproj_kernel),
                        hipFuncAttributeMaxDynamicSharedMemorySize, 131072);
    hipFuncSetAttribute(reinterpret_cast<const void*>(&rnn_kernel),
                        hipFuncAttributeMaxDynamicSharedMemorySize, 135168);
    xproj_kernel<<<dim3(1024, 4, 1), 512, 131072, stream>>>(
        text, emb, W_ih, b_ih, b_hh, xpbf);
    rnn_kernel<<<64, 256, 135168, stream>>>(
        W_hh, xpbf, fc_w, fc_b, hbuf, bar, out);

    if (probe_ok) {
        wprep_pack<<<32, 256, 0, stream>>>(W_hh, Wp);
        hipFuncSetAttribute(reinterpret_cast<const void*>(&rnn_probeD2),
                            hipFuncAttributeMaxDynamicSharedMemorySize, 163840);
        hipFuncSetAttribute(reinterpret_cast<const void*>(&rnn_probeD3),
                            hipFuncAttributeMaxDynamicSharedMemorySize, 163840);
        rnn_probeD2<<<16, 512, 163840, stream>>>(W_hh, Wp, xpbf, hbuf);
        rnn_probeD3<<<16, 512, 163840, stream>>>(W_hh, Wp, xpbf, hbuf);
    }
}